// Round 1
// baseline (547.280 us; speedup 1.0000x reference)
//
#include <hip/hip_runtime.h>
#include <hip/hip_bf16.h>
#include <cstdint>
#include <cstddef>

typedef unsigned short u16;
typedef unsigned int u32;
typedef __attribute__((ext_vector_type(4))) float f32x4;
typedef __attribute__((ext_vector_type(8))) __bf16 bf16x8;

#define EPS_F 1.1920928955078125e-07f
#define INV_SQRT_D 0.08838834764831845f

__device__ __forceinline__ u16 f2bf(float f) {
  union { float f; u32 u; } v; v.f = f;
  u32 r = v.u + 0x7fffu + ((v.u >> 16) & 1u);
  return (u16)(r >> 16);
}

__device__ __forceinline__ ushort4 pack_bf4(float a, float b, float c, float d) {
  ushort4 o; o.x = f2bf(a); o.y = f2bf(b); o.z = f2bf(c); o.w = f2bf(d); return o;
}

__device__ __forceinline__ void gload_lds16(const void* g, void* l) {
  __builtin_amdgcn_global_load_lds((const __attribute__((address_space(1))) u32*)g,
                                   (__attribute__((address_space(3))) u32*)l, 16, 0, 0);
}

// ---------------- cast f32 -> bf16 ----------------
__global__ __launch_bounds__(256) void k_cast_bf16(const float* __restrict__ src,
                                                   u16* __restrict__ dst, int n) {
  int i = (blockIdx.x * 256 + threadIdx.x) * 4;
  if (i + 3 < n) {
    float4 v = *(const float4*)(src + i);
    *(ushort4*)(dst + i) = pack_bf4(v.x, v.y, v.z, v.w);
  }
}

// ---------------- bf16 GEMM, C = A * B^T (both row-major along K) ----------------
// A: M x K bf16, Bw: N x K bf16, C: M x N fp32.  128x128 tile, BK=32, 4 waves.
__global__ __launch_bounds__(256) void k_gemm_bt(const u16* __restrict__ A,
                                                 const u16* __restrict__ Bw,
                                                 float* __restrict__ C,
                                                 int M, int N, int K) {
  __shared__ __align__(16) u16 As[128 * 32];
  __shared__ __align__(16) u16 Bs[128 * 32];
  const int tid = threadIdx.x;
  const int lane = tid & 63;
  const int wid = tid >> 6;
  const int wm = wid >> 1, wn = wid & 1;
  const int l15 = lane & 15, l4 = lane >> 4;

  f32x4 acc[4][4];
#pragma unroll
  for (int i = 0; i < 4; ++i)
#pragma unroll
    for (int j = 0; j < 4; ++j) acc[i][j] = {0.f, 0.f, 0.f, 0.f};

  const u16* Ab = A + (size_t)blockIdx.x * 128 * K;
  const u16* Bb = Bw + (size_t)blockIdx.y * 128 * K;
  const int lrow = lane >> 2;                         // 0..15 row within chunk
  // LDS block swizzle: content at (row, cb) = global (row, cb ^ ((row>>1)&3))
  const int scol = ((lane & 3) ^ ((lane >> 3) & 3)) * 8;  // (lrow>>1)&3 == (lane>>3)&3
  const int rswz = (l15 >> 1) & 3;                    // read-side swizzle key

  for (int k0 = 0; k0 < K; k0 += 32) {
    __syncthreads();
#pragma unroll
    for (int p = 0; p < 2; ++p) {
      const int chunk = wid * 2 + p;                  // 0..7, 16 rows each
      const int row = chunk * 16 + lrow;
      gload_lds16(Ab + (size_t)row * K + k0 + scol, &As[chunk * 512]);
      gload_lds16(Bb + (size_t)row * K + k0 + scol, &Bs[chunk * 512]);
    }
    __syncthreads();
    bf16x8 af[4], bfv[4];
#pragma unroll
    for (int i = 0; i < 4; ++i) {
      const int cb = (l4 ^ rswz) * 8;
      af[i]  = *(const bf16x8*)&As[(wm * 64 + i * 16 + l15) * 32 + cb];
      bfv[i] = *(const bf16x8*)&Bs[(wn * 64 + i * 16 + l15) * 32 + cb];
    }
#pragma unroll
    for (int i = 0; i < 4; ++i)
#pragma unroll
      for (int j = 0; j < 4; ++j)
        acc[i][j] = __builtin_amdgcn_mfma_f32_16x16x32_bf16(af[i], bfv[j], acc[i][j], 0, 0, 0);
  }

  const int r0 = blockIdx.x * 128 + wm * 64 + l4 * 4;
  const int c0 = blockIdx.y * 128 + wn * 64 + l15;
#pragma unroll
  for (int i = 0; i < 4; ++i)
#pragma unroll
    for (int j = 0; j < 4; ++j) {
      float* Cp = C + (size_t)(r0 + i * 16) * N + c0 + j * 16;
#pragma unroll
      for (int r = 0; r < 4; ++r) Cp[(size_t)r * N] = acc[i][j][r];
    }
}

// ---------------- rope + rmsnorm + scale + cast ----------------
// qkv: [4096][6144] fp32 (q|k|v). Writes qb,kb,vb as bf16 [b][h][t][128].
__global__ __launch_bounds__(256) void k_rope_rms(const float* __restrict__ qkv,
                                                  const float* __restrict__ cosp,
                                                  const float* __restrict__ sinp,
                                                  u16* __restrict__ qb, u16* __restrict__ kb,
                                                  u16* __restrict__ vb) {
  const int T = 2048;
  const int m = blockIdx.x;            // 0..4095 = b*T + t
  const int b = m >> 11;
  const int t = m & 2047;
  const int tid = threadIdx.x;
  const int h = tid >> 4;
  const int d0 = (tid & 15) * 4;
  const size_t ro = (size_t)m * 6144 + h * 128;

  float4 q1 = *(const float4*)(qkv + ro + d0);
  float4 q2 = *(const float4*)(qkv + ro + d0 + 64);
  float4 k1 = *(const float4*)(qkv + ro + 2048 + d0);
  float4 k2 = *(const float4*)(qkv + ro + 2048 + d0 + 64);
  float4 v1 = *(const float4*)(qkv + ro + 4096 + d0);
  float4 v2 = *(const float4*)(qkv + ro + 4096 + d0 + 64);
  float4 cs = *(const float4*)(cosp + (size_t)t * 64 + d0);
  float4 sn = *(const float4*)(sinp + (size_t)t * 64 + d0);

  float sq = q1.x*q1.x + q1.y*q1.y + q1.z*q1.z + q1.w*q1.w
           + q2.x*q2.x + q2.y*q2.y + q2.z*q2.z + q2.w*q2.w;
  float sk = k1.x*k1.x + k1.y*k1.y + k1.z*k1.z + k1.w*k1.w
           + k2.x*k2.x + k2.y*k2.y + k2.z*k2.z + k2.w*k2.w;
#pragma unroll
  for (int o = 1; o < 16; o <<= 1) {
    sq += __shfl_xor(sq, o, 64);
    sk += __shfl_xor(sk, o, 64);
  }
  // rope is a rotation -> sum of squares invariant: use pre-rope values
  const float rq = rsqrtf(sq * (1.f / 128.f) + EPS_F) * INV_SQRT_D;  // fold 1/sqrt(D)
  const float rk = rsqrtf(sk * (1.f / 128.f) + EPS_F);

  const size_t ob = ((size_t)(b * 16 + h) * T + t) * 128 + d0;
  *(ushort4*)(qb + ob) = pack_bf4((q1.x*cs.x + q2.x*sn.x) * rq, (q1.y*cs.y + q2.y*sn.y) * rq,
                                  (q1.z*cs.z + q2.z*sn.z) * rq, (q1.w*cs.w + q2.w*sn.w) * rq);
  *(ushort4*)(qb + ob + 64) = pack_bf4((q2.x*cs.x - q1.x*sn.x) * rq, (q2.y*cs.y - q1.y*sn.y) * rq,
                                       (q2.z*cs.z - q1.z*sn.z) * rq, (q2.w*cs.w - q1.w*sn.w) * rq);
  *(ushort4*)(kb + ob) = pack_bf4((k1.x*cs.x + k2.x*sn.x) * rk, (k1.y*cs.y + k2.y*sn.y) * rk,
                                  (k1.z*cs.z + k2.z*sn.z) * rk, (k1.w*cs.w + k2.w*sn.w) * rk);
  *(ushort4*)(kb + ob + 64) = pack_bf4((k2.x*cs.x - k1.x*sn.x) * rk, (k2.y*cs.y - k1.y*sn.y) * rk,
                                       (k2.z*cs.z - k1.z*sn.z) * rk, (k2.w*cs.w - k1.w*sn.w) * rk);
  *(ushort4*)(vb + ob) = pack_bf4(v1.x, v1.y, v1.z, v1.w);
  *(ushort4*)(vb + ob + 64) = pack_bf4(v2.x, v2.y, v2.z, v2.w);
}

// ---------------- V transpose: [bh][t][d] -> [bh][d][t] ----------------
__global__ __launch_bounds__(256) void k_transpose_v(const u16* __restrict__ vb,
                                                     u16* __restrict__ vt) {
  const int T = 2048;
  __shared__ u16 tile[32][33];
  const int bh = blockIdx.z;
  const int t0 = blockIdx.x * 32;
  const int d0 = blockIdx.y * 32;
  const int tx = threadIdx.x & 31;
  const int ty = threadIdx.x >> 5;
  const size_t base = (size_t)bh * T * 128;
#pragma unroll
  for (int i = 0; i < 4; ++i)
    tile[ty + i * 8][tx] = vb[base + (size_t)(t0 + ty + i * 8) * 128 + d0 + tx];
  __syncthreads();
#pragma unroll
  for (int i = 0; i < 4; ++i)
    vt[base + (size_t)(d0 + ty + i * 8) * T + t0 + tx] = tile[tx][ty + i * 8];
}

// ---------------- causal flash attention ----------------
// qb,kb: [bh][t][128] bf16 (q pre-scaled).  vt: [bh][d][t] bf16.  y: [b][t][h*128+d] bf16.
__global__ __launch_bounds__(256) void k_attn(const u16* __restrict__ qb,
                                              const u16* __restrict__ kb,
                                              const u16* __restrict__ vt,
                                              u16* __restrict__ y) {
  const int T = 2048;
  __shared__ __align__(16) u16 Ks[64 * 128];   // [kv][d], (row&7) block-swizzled
  __shared__ __align__(16) u16 Vs[128 * 64];   // [d][kv], (row&7) block-swizzled
  __shared__ __align__(16) u16 Ps[64 * 72];    // per-wave rows, +8 pad

  const int tid = threadIdx.x;
  const int lane = tid & 63;
  const int wid = tid >> 6;
  const int bh = blockIdx.y;
  const int q0 = blockIdx.x * 64;
  const int b = bh >> 4, h = bh & 15;
  const size_t hb = (size_t)bh * T * 128;
  const int l15 = lane & 15, l4 = lane >> 4;

  bf16x8 qf[4];
  {
    const int qrow = q0 + wid * 16 + l15;
#pragma unroll
    for (int ki = 0; ki < 4; ++ki)
      qf[ki] = *(const bf16x8*)(qb + hb + (size_t)qrow * 128 + ki * 32 + l4 * 8);
  }

  float mrow[4], lsum[4];
  f32x4 oacc[8];
#pragma unroll
  for (int r = 0; r < 4; ++r) { mrow[r] = -INFINITY; lsum[r] = 0.f; }
#pragma unroll
  for (int d = 0; d < 8; ++d) oacc[d] = {0.f, 0.f, 0.f, 0.f};

  const int niter = blockIdx.x + 1;
  for (int it = 0; it < niter; ++it) {
    const int kv0 = it * 64;
    __syncthreads();
#pragma unroll
    for (int p = 0; p < 4; ++p) {
      const int chunk = wid * 4 + p;               // 0..15
      {
        const int row = chunk * 4 + l4;            // K: 4 rows (256B) per chunk
        const int scb = l15 ^ (row & 7);
        gload_lds16(kb + hb + (size_t)(kv0 + row) * 128 + scb * 8, &Ks[chunk * 512]);
      }
      {
        const int row = chunk * 8 + (lane >> 3);   // V: 8 rows (128B) per chunk
        const int scb = (lane & 7) ^ (row & 7);
        gload_lds16(vt + hb + (size_t)row * T + kv0 + scb * 8, &Vs[chunk * 512]);
      }
    }
    __syncthreads();

    // S = q K^T
    f32x4 s[4];
#pragma unroll
    for (int ni = 0; ni < 4; ++ni) {
      s[ni] = {0.f, 0.f, 0.f, 0.f};
      const int r = ni * 16 + l15;
#pragma unroll
      for (int ki = 0; ki < 4; ++ki) {
        const int cb = (ki * 4 + l4) ^ (r & 7);
        bf16x8 kf = *(const bf16x8*)&Ks[r * 128 + cb * 8];
        s[ni] = __builtin_amdgcn_mfma_f32_16x16x32_bf16(qf[ki], kf, s[ni], 0, 0, 0);
      }
    }

    if (kv0 == q0) {  // diagonal tile: causal mask
      const int grow = q0 + wid * 16 + l4 * 4;
      const int gcol = kv0 + l15;
#pragma unroll
      for (int ni = 0; ni < 4; ++ni)
#pragma unroll
        for (int r = 0; r < 4; ++r)
          if (gcol + ni * 16 > grow + r) s[ni][r] = -INFINITY;
    }

    // online softmax (rows live across 16-lane groups)
    float pv[4][4];
    float alpha[4];
#pragma unroll
    for (int r = 0; r < 4; ++r) {
      float mx = fmaxf(fmaxf(s[0][r], s[1][r]), fmaxf(s[2][r], s[3][r]));
#pragma unroll
      for (int o = 1; o < 16; o <<= 1) mx = fmaxf(mx, __shfl_xor(mx, o, 64));
      const float mnew = fmaxf(mrow[r], mx);
      alpha[r] = __expf(mrow[r] - mnew);
      mrow[r] = mnew;
      float ps = 0.f;
#pragma unroll
      for (int ni = 0; ni < 4; ++ni) {
        const float p = __expf(s[ni][r] - mnew);
        pv[ni][r] = p;
        ps += p;
      }
#pragma unroll
      for (int o = 1; o < 16; o <<= 1) ps += __shfl_xor(ps, o, 64);
      lsum[r] = lsum[r] * alpha[r] + ps;
    }
#pragma unroll
    for (int d = 0; d < 8; ++d) {
      f32x4 tv = oacc[d];
      tv[0] *= alpha[0]; tv[1] *= alpha[1]; tv[2] *= alpha[2]; tv[3] *= alpha[3];
      oacc[d] = tv;
    }
    // P -> LDS (per-wave region), transpose C-layout -> A-layout
#pragma unroll
    for (int ni = 0; ni < 4; ++ni)
#pragma unroll
      for (int r = 0; r < 4; ++r)
        Ps[(wid * 16 + l4 * 4 + r) * 72 + ni * 16 + l15] = f2bf(pv[ni][r]);
    __syncthreads();

    // O += P V
#pragma unroll
    for (int k2 = 0; k2 < 2; ++k2) {
      bf16x8 pa = *(const bf16x8*)&Ps[(wid * 16 + l15) * 72 + k2 * 32 + l4 * 8];
#pragma unroll
      for (int dt = 0; dt < 8; ++dt) {
        const int r = dt * 16 + l15;
        const int cb = (k2 * 4 + l4) ^ (r & 7);
        bf16x8 vf = *(const bf16x8*)&Vs[r * 64 + cb * 8];
        oacc[dt] = __builtin_amdgcn_mfma_f32_16x16x32_bf16(pa, vf, oacc[dt], 0, 0, 0);
      }
    }
  }

#pragma unroll
  for (int r = 0; r < 4; ++r) {
    const float inv = 1.f / lsum[r];
    const size_t yo = ((size_t)(b * T) + q0 + wid * 16 + l4 * 4 + r) * 2048 + h * 128;
#pragma unroll
    for (int dt = 0; dt < 8; ++dt)
      y[yo + dt * 16 + l15] = f2bf(oacc[dt][r] * inv);
  }
}

// ---------------- launcher ----------------
extern "C" void kernel_launch(void* const* d_in, const int* in_sizes, int n_in,
                              void* d_out, int out_size, void* d_ws, size_t ws_size,
                              hipStream_t stream) {
  const float* x     = (const float*)d_in[0];
  const float* cosp  = (const float*)d_in[1];
  const float* sinp  = (const float*)d_in[2];
  const float* wq    = (const float*)d_in[3];
  const float* wk    = (const float*)d_in[4];
  const float* wv    = (const float*)d_in[5];
  const float* wproj = (const float*)d_in[6];
  float* out = (float*)d_out;

  const int T = 2048, C = 2048;
  const int M = 2 * T;           // 4096 rows
  const int N1 = 3 * C;          // 6144 fused qkv cols

  char* ws = (char*)d_ws;
  size_t off = 0;
  auto take = [&](size_t bytes) -> char* {
    char* p = ws + off;
    off += (bytes + 255) & ~(size_t)255;
    return p;
  };
  u16* xb    = (u16*)take((size_t)M * C * 2);
  u16* wqkvb = (u16*)take((size_t)N1 * C * 2);
  u16* wpb   = (u16*)take((size_t)C * C * 2);
  float* qkv = (float*)take((size_t)M * N1 * 4);
  u16* qb    = (u16*)take((size_t)M * C * 2);
  u16* kb    = (u16*)take((size_t)M * C * 2);
  u16* vb    = (u16*)take((size_t)M * C * 2);
  u16* vt    = (u16*)take((size_t)M * C * 2);
  u16* yb    = (u16*)take((size_t)M * C * 2);
  (void)ws_size; (void)in_sizes; (void)n_in; (void)out_size;

  const int nx = M * C;          // 8388608
  const int nw = C * C;          // 4194304
  k_cast_bf16<<<nx / 1024, 256, 0, stream>>>(x, xb, nx);
  k_cast_bf16<<<nw / 1024, 256, 0, stream>>>(wq, wqkvb, nw);
  k_cast_bf16<<<nw / 1024, 256, 0, stream>>>(wk, wqkvb + (size_t)C * C, nw);
  k_cast_bf16<<<nw / 1024, 256, 0, stream>>>(wv, wqkvb + (size_t)2 * C * C, nw);
  k_cast_bf16<<<nw / 1024, 256, 0, stream>>>(wproj, wpb, nw);

  k_gemm_bt<<<dim3(M / 128, N1 / 128), 256, 0, stream>>>(xb, wqkvb, qkv, M, N1, C);
  k_rope_rms<<<M, 256, 0, stream>>>(qkv, cosp, sinp, qb, kb, vb);
  k_transpose_v<<<dim3(T / 32, 128 / 32, 32), 256, 0, stream>>>(vb, vt);
  k_attn<<<dim3(T / 64, 32), 256, 0, stream>>>(qb, kb, vt, yb);
  k_gemm_bt<<<dim3(M / 128, C / 128), 256, 0, stream>>>(yb, wpb, out, M, C, C);
}

// Round 2
// 472.670 us; speedup vs baseline: 1.1578x; 1.1578x over previous
//
#include <hip/hip_runtime.h>
#include <hip/hip_bf16.h>
#include <cstdint>
#include <cstddef>

typedef unsigned short u16;
typedef unsigned int u32;
typedef __attribute__((ext_vector_type(4))) float f32x4;
typedef __attribute__((ext_vector_type(8))) __bf16 bf16x8;

#define EPS_F 1.1920928955078125e-07f
#define INV_SQRT_D 0.08838834764831845f
#define LOG2E 1.4426950408889634f

__device__ __forceinline__ u16 f2bf(float f) {
  union { float f; u32 u; } v; v.f = f;
  u32 r = v.u + 0x7fffu + ((v.u >> 16) & 1u);
  return (u16)(r >> 16);
}

__device__ __forceinline__ ushort4 pack_bf4(float a, float b, float c, float d) {
  ushort4 o; o.x = f2bf(a); o.y = f2bf(b); o.z = f2bf(c); o.w = f2bf(d); return o;
}

__device__ __forceinline__ void gload_lds16(const void* g, void* l) {
  __builtin_amdgcn_global_load_lds((const __attribute__((address_space(1))) u32*)g,
                                   (__attribute__((address_space(3))) u32*)l, 16, 0, 0);
}

// ---------------- cast f32 -> bf16 ----------------
__global__ __launch_bounds__(256) void k_cast_bf16(const float* __restrict__ src,
                                                   u16* __restrict__ dst, int n) {
  int i = (blockIdx.x * 256 + threadIdx.x) * 4;
  if (i + 3 < n) {
    float4 v = *(const float4*)(src + i);
    *(ushort4*)(dst + i) = pack_bf4(v.x, v.y, v.z, v.w);
  }
}

// ---------------- bf16 GEMM, C = A * B^T (both row-major along K) ----------------
__global__ __launch_bounds__(256) void k_gemm_bt(const u16* __restrict__ A,
                                                 const u16* __restrict__ Bw,
                                                 float* __restrict__ C,
                                                 int M, int N, int K) {
  __shared__ __align__(16) u16 As[128 * 32];
  __shared__ __align__(16) u16 Bs[128 * 32];
  const int tid = threadIdx.x;
  const int lane = tid & 63;
  const int wid = tid >> 6;
  const int wm = wid >> 1, wn = wid & 1;
  const int l15 = lane & 15, l4 = lane >> 4;

  f32x4 acc[4][4];
#pragma unroll
  for (int i = 0; i < 4; ++i)
#pragma unroll
    for (int j = 0; j < 4; ++j) acc[i][j] = {0.f, 0.f, 0.f, 0.f};

  const u16* Ab = A + (size_t)blockIdx.x * 128 * K;
  const u16* Bb = Bw + (size_t)blockIdx.y * 128 * K;
  const int lrow = lane >> 2;
  const int scol = ((lane & 3) ^ ((lane >> 3) & 3)) * 8;
  const int rswz = (l15 >> 1) & 3;

  for (int k0 = 0; k0 < K; k0 += 32) {
    __syncthreads();
#pragma unroll
    for (int p = 0; p < 2; ++p) {
      const int chunk = wid * 2 + p;
      const int row = chunk * 16 + lrow;
      gload_lds16(Ab + (size_t)row * K + k0 + scol, &As[chunk * 512]);
      gload_lds16(Bb + (size_t)row * K + k0 + scol, &Bs[chunk * 512]);
    }
    __syncthreads();
    bf16x8 af[4], bfv[4];
#pragma unroll
    for (int i = 0; i < 4; ++i) {
      const int cb = (l4 ^ rswz) * 8;
      af[i]  = *(const bf16x8*)&As[(wm * 64 + i * 16 + l15) * 32 + cb];
      bfv[i] = *(const bf16x8*)&Bs[(wn * 64 + i * 16 + l15) * 32 + cb];
    }
#pragma unroll
    for (int i = 0; i < 4; ++i)
#pragma unroll
      for (int j = 0; j < 4; ++j)
        acc[i][j] = __builtin_amdgcn_mfma_f32_16x16x32_bf16(af[i], bfv[j], acc[i][j], 0, 0, 0);
  }

  const int r0 = blockIdx.x * 128 + wm * 64 + l4 * 4;
  const int c0 = blockIdx.y * 128 + wn * 64 + l15;
#pragma unroll
  for (int i = 0; i < 4; ++i)
#pragma unroll
    for (int j = 0; j < 4; ++j) {
      float* Cp = C + (size_t)(r0 + i * 16) * N + c0 + j * 16;
#pragma unroll
      for (int r = 0; r < 4; ++r) Cp[(size_t)r * N] = acc[i][j][r];
    }
}

// ---------------- rope + rmsnorm + scale + cast ----------------
__global__ __launch_bounds__(256) void k_rope_rms(const float* __restrict__ qkv,
                                                  const float* __restrict__ cosp,
                                                  const float* __restrict__ sinp,
                                                  u16* __restrict__ qb, u16* __restrict__ kb,
                                                  u16* __restrict__ vb) {
  const int T = 2048;
  const int m = blockIdx.x;
  const int b = m >> 11;
  const int t = m & 2047;
  const int tid = threadIdx.x;
  const int h = tid >> 4;
  const int d0 = (tid & 15) * 4;
  const size_t ro = (size_t)m * 6144 + h * 128;

  float4 q1 = *(const float4*)(qkv + ro + d0);
  float4 q2 = *(const float4*)(qkv + ro + d0 + 64);
  float4 k1 = *(const float4*)(qkv + ro + 2048 + d0);
  float4 k2 = *(const float4*)(qkv + ro + 2048 + d0 + 64);
  float4 v1 = *(const float4*)(qkv + ro + 4096 + d0);
  float4 v2 = *(const float4*)(qkv + ro + 4096 + d0 + 64);
  float4 cs = *(const float4*)(cosp + (size_t)t * 64 + d0);
  float4 sn = *(const float4*)(sinp + (size_t)t * 64 + d0);

  float sq = q1.x*q1.x + q1.y*q1.y + q1.z*q1.z + q1.w*q1.w
           + q2.x*q2.x + q2.y*q2.y + q2.z*q2.z + q2.w*q2.w;
  float sk = k1.x*k1.x + k1.y*k1.y + k1.z*k1.z + k1.w*k1.w
           + k2.x*k2.x + k2.y*k2.y + k2.z*k2.z + k2.w*k2.w;
#pragma unroll
  for (int o = 1; o < 16; o <<= 1) {
    sq += __shfl_xor(sq, o, 64);
    sk += __shfl_xor(sk, o, 64);
  }
  // rope is a rotation -> sum of squares invariant; fold 1/sqrt(D) and log2(e) into q
  const float rq = rsqrtf(sq * (1.f / 128.f) + EPS_F) * (INV_SQRT_D * LOG2E);
  const float rk = rsqrtf(sk * (1.f / 128.f) + EPS_F);

  const size_t ob = ((size_t)(b * 16 + h) * T + t) * 128 + d0;
  *(ushort4*)(qb + ob) = pack_bf4((q1.x*cs.x + q2.x*sn.x) * rq, (q1.y*cs.y + q2.y*sn.y) * rq,
                                  (q1.z*cs.z + q2.z*sn.z) * rq, (q1.w*cs.w + q2.w*sn.w) * rq);
  *(ushort4*)(qb + ob + 64) = pack_bf4((q2.x*cs.x - q1.x*sn.x) * rq, (q2.y*cs.y - q1.y*sn.y) * rq,
                                       (q2.z*cs.z - q1.z*sn.z) * rq, (q2.w*cs.w - q1.w*sn.w) * rq);
  *(ushort4*)(kb + ob) = pack_bf4((k1.x*cs.x + k2.x*sn.x) * rk, (k1.y*cs.y + k2.y*sn.y) * rk,
                                  (k1.z*cs.z + k2.z*sn.z) * rk, (k1.w*cs.w + k2.w*sn.w) * rk);
  *(ushort4*)(kb + ob + 64) = pack_bf4((k2.x*cs.x - k1.x*sn.x) * rk, (k2.y*cs.y - k1.y*sn.y) * rk,
                                       (k2.z*cs.z - k1.z*sn.z) * rk, (k2.w*cs.w - k1.w*sn.w) * rk);
  *(ushort4*)(vb + ob) = pack_bf4(v1.x, v1.y, v1.z, v1.w);
  *(ushort4*)(vb + ob + 64) = pack_bf4(v2.x, v2.y, v2.z, v2.w);
}

// ---------------- V transpose: [bh][t][d] -> [bh][d][t] ----------------
__global__ __launch_bounds__(256) void k_transpose_v(const u16* __restrict__ vb,
                                                     u16* __restrict__ vt) {
  const int T = 2048;
  __shared__ u16 tile[32][33];
  const int bh = blockIdx.z;
  const int t0 = blockIdx.x * 32;
  const int d0 = blockIdx.y * 32;
  const int tx = threadIdx.x & 31;
  const int ty = threadIdx.x >> 5;
  const size_t base = (size_t)bh * T * 128;
#pragma unroll
  for (int i = 0; i < 4; ++i)
    tile[ty + i * 8][tx] = vb[base + (size_t)(t0 + ty + i * 8) * 128 + d0 + tx];
  __syncthreads();
#pragma unroll
  for (int i = 0; i < 4; ++i)
    vt[base + (size_t)(d0 + ty + i * 8) * T + t0 + tx] = tile[tx][ty + i * 8];
}

// ---------------- causal flash attention ----------------
// Paired q-tiles (i, 31-i) per block -> 33 KV-iters per block, balanced.
// Double-buffered K/V staging, 1 raw barrier per KV-iter.
// qb,kb: [bh][t][128] bf16 (q pre-scaled by 1/sqrt(D)*log2e).  vt: [bh][d][t].
__global__ __launch_bounds__(256) void k_attn(const u16* __restrict__ qb,
                                              const u16* __restrict__ kb,
                                              const u16* __restrict__ vt,
                                              u16* __restrict__ y) {
  const int T = 2048;
  __shared__ __align__(16) u16 Ks[2][64 * 128];  // [kv][d], (row&7) block-swizzled
  __shared__ __align__(16) u16 Vs[2][128 * 64];  // [d][kv], (row&7) block-swizzled
  __shared__ __align__(16) u16 Ps[64 * 72];      // per-wave private rows, +8 pad

  const int tid = threadIdx.x;
  const int lane = tid & 63;
  const int wid = tid >> 6;
  const int bh = blockIdx.y;
  const int b = bh >> 4, h = bh & 15;
  const size_t hb = (size_t)bh * T * 128;
  const int l15 = lane & 15, l4 = lane >> 4;

  auto stage = [&](int it, int buf) {
#pragma unroll
    for (int p = 0; p < 4; ++p) {
      const int chunk = wid * 4 + p;               // 0..15
      {
        const int row = chunk * 4 + l4;            // K: 4 rows per chunk
        const int scb = l15 ^ (row & 7);
        gload_lds16(kb + hb + (size_t)(it * 64 + row) * 128 + scb * 8, &Ks[buf][chunk * 512]);
      }
      {
        const int row = chunk * 8 + (lane >> 3);   // V: 8 rows per chunk
        const int scb = (lane & 7) ^ (row & 7);
        gload_lds16(vt + hb + (size_t)row * T + it * 64 + scb * 8, &Vs[buf][chunk * 512]);
      }
    }
  };

#pragma unroll 1
  for (int ph = 0; ph < 2; ++ph) {
    const int qt = (ph == 0) ? (int)blockIdx.x : 31 - (int)blockIdx.x;
    const int q0 = qt * 64;
    const int niter = qt + 1;

    bf16x8 qf[4];
    {
      const int qrow = q0 + wid * 16 + l15;
#pragma unroll
      for (int ki = 0; ki < 4; ++ki)
        qf[ki] = *(const bf16x8*)(qb + hb + (size_t)qrow * 128 + ki * 32 + l4 * 8);
    }

    float mrow[4], lsum[4];
    f32x4 oacc[8];
#pragma unroll
    for (int r = 0; r < 4; ++r) { mrow[r] = -INFINITY; lsum[r] = 0.f; }
#pragma unroll
    for (int d = 0; d < 8; ++d) oacc[d] = {0.f, 0.f, 0.f, 0.f};

    stage(0, 0);
    asm volatile("s_waitcnt vmcnt(0)" ::: "memory");
    __builtin_amdgcn_s_barrier();
    __builtin_amdgcn_sched_barrier(0);

    int cur = 0;
#pragma unroll 1
    for (int it = 0; it < niter; ++it) {
      if (it + 1 < niter) stage(it + 1, cur ^ 1);

      // S = q K^T
      f32x4 s[4];
#pragma unroll
      for (int ni = 0; ni < 4; ++ni) {
        s[ni] = {0.f, 0.f, 0.f, 0.f};
        const int r = ni * 16 + l15;
#pragma unroll
        for (int ki = 0; ki < 4; ++ki) {
          const int cb = (ki * 4 + l4) ^ (r & 7);
          bf16x8 kf = *(const bf16x8*)&Ks[cur][r * 128 + cb * 8];
          s[ni] = __builtin_amdgcn_mfma_f32_16x16x32_bf16(qf[ki], kf, s[ni], 0, 0, 0);
        }
      }

      if (it == niter - 1) {  // diagonal tile: causal mask
        const int grow = q0 + wid * 16 + l4 * 4;
        const int gcol = it * 64 + l15;
#pragma unroll
        for (int ni = 0; ni < 4; ++ni)
#pragma unroll
          for (int r = 0; r < 4; ++r)
            if (gcol + ni * 16 > grow + r) s[ni][r] = -INFINITY;
      }

      // online softmax (log2 domain; rows live across 16-lane groups)
      float pv[4][4];
      float alpha[4];
#pragma unroll
      for (int r = 0; r < 4; ++r) {
        float mx = fmaxf(fmaxf(s[0][r], s[1][r]), fmaxf(s[2][r], s[3][r]));
#pragma unroll
        for (int o = 1; o < 16; o <<= 1) mx = fmaxf(mx, __shfl_xor(mx, o, 64));
        const float mnew = fmaxf(mrow[r], mx);
        alpha[r] = exp2f(mrow[r] - mnew);
        mrow[r] = mnew;
        float ps = 0.f;
#pragma unroll
        for (int ni = 0; ni < 4; ++ni) {
          const float p = exp2f(s[ni][r] - mnew);
          pv[ni][r] = p;
          ps += p;
        }
#pragma unroll
        for (int o = 1; o < 16; o <<= 1) ps += __shfl_xor(ps, o, 64);
        lsum[r] = lsum[r] * alpha[r] + ps;
      }
#pragma unroll
      for (int d = 0; d < 8; ++d) {
        f32x4 tv = oacc[d];
        tv[0] *= alpha[0]; tv[1] *= alpha[1]; tv[2] *= alpha[2]; tv[3] *= alpha[3];
        oacc[d] = tv;
      }
      // P -> LDS (per-wave private region; intra-wave ordering via lgkmcnt, no barrier)
#pragma unroll
      for (int ni = 0; ni < 4; ++ni)
#pragma unroll
        for (int r = 0; r < 4; ++r)
          Ps[(wid * 16 + l4 * 4 + r) * 72 + ni * 16 + l15] = f2bf(pv[ni][r]);

      // O += P V
#pragma unroll
      for (int k2 = 0; k2 < 2; ++k2) {
        bf16x8 pa = *(const bf16x8*)&Ps[(wid * 16 + l15) * 72 + k2 * 32 + l4 * 8];
#pragma unroll
        for (int dt = 0; dt < 8; ++dt) {
          const int r = dt * 16 + l15;
          const int cb = (k2 * 4 + l4) ^ (r & 7);
          bf16x8 vf = *(const bf16x8*)&Vs[cur][r * 64 + cb * 8];
          oacc[dt] = __builtin_amdgcn_mfma_f32_16x16x32_bf16(pa, vf, oacc[dt], 0, 0, 0);
        }
      }

      asm volatile("s_waitcnt vmcnt(0)" ::: "memory");
      __builtin_amdgcn_s_barrier();
      __builtin_amdgcn_sched_barrier(0);
      cur ^= 1;
    }

#pragma unroll
    for (int r = 0; r < 4; ++r) {
      const float inv = 1.f / lsum[r];
      const size_t yo = ((size_t)(b * T) + q0 + wid * 16 + l4 * 4 + r) * 2048 + h * 128;
#pragma unroll
      for (int dt = 0; dt < 8; ++dt)
        y[yo + dt * 16 + l15] = f2bf(oacc[dt][r] * inv);
    }
  }
}

// ---------------- launcher ----------------
extern "C" void kernel_launch(void* const* d_in, const int* in_sizes, int n_in,
                              void* d_out, int out_size, void* d_ws, size_t ws_size,
                              hipStream_t stream) {
  const float* x     = (const float*)d_in[0];
  const float* cosp  = (const float*)d_in[1];
  const float* sinp  = (const float*)d_in[2];
  const float* wq    = (const float*)d_in[3];
  const float* wk    = (const float*)d_in[4];
  const float* wv    = (const float*)d_in[5];
  const float* wproj = (const float*)d_in[6];
  float* out = (float*)d_out;

  const int T = 2048, C = 2048;
  const int M = 2 * T;
  const int N1 = 3 * C;

  char* ws = (char*)d_ws;
  size_t off = 0;
  auto take = [&](size_t bytes) -> char* {
    char* p = ws + off;
    off += (bytes + 255) & ~(size_t)255;
    return p;
  };
  u16* xb    = (u16*)take((size_t)M * C * 2);
  u16* wqkvb = (u16*)take((size_t)N1 * C * 2);
  u16* wpb   = (u16*)take((size_t)C * C * 2);
  float* qkv = (float*)take((size_t)M * N1 * 4);
  u16* qb    = (u16*)take((size_t)M * C * 2);
  u16* kb    = (u16*)take((size_t)M * C * 2);
  u16* vb    = (u16*)take((size_t)M * C * 2);
  u16* vt    = (u16*)take((size_t)M * C * 2);
  u16* yb    = (u16*)take((size_t)M * C * 2);
  (void)ws_size; (void)in_sizes; (void)n_in; (void)out_size;

  const int nx = M * C;
  const int nw = C * C;
  k_cast_bf16<<<nx / 1024, 256, 0, stream>>>(x, xb, nx);
  k_cast_bf16<<<nw / 1024, 256, 0, stream>>>(wq, wqkvb, nw);
  k_cast_bf16<<<nw / 1024, 256, 0, stream>>>(wk, wqkvb + (size_t)C * C, nw);
  k_cast_bf16<<<nw / 1024, 256, 0, stream>>>(wv, wqkvb + (size_t)2 * C * C, nw);
  k_cast_bf16<<<nw / 1024, 256, 0, stream>>>(wproj, wpb, nw);

  k_gemm_bt<<<dim3(M / 128, N1 / 128), 256, 0, stream>>>(xb, wqkvb, qkv, M, N1, C);
  k_rope_rms<<<M, 256, 0, stream>>>(qkv, cosp, sinp, qb, kb, vb);
  k_transpose_v<<<dim3(T / 32, 128 / 32, 32), 256, 0, stream>>>(vb, vt);
  k_attn<<<dim3(16, 32), 256, 0, stream>>>(qb, kb, vt, yb);
  k_gemm_bt<<<dim3(M / 128, C / 128), 256, 0, stream>>>(yb, wpb, out, M, C, C);
}

// Round 3
// 447.765 us; speedup vs baseline: 1.2222x; 1.0556x over previous
//
#include <hip/hip_runtime.h>
#include <hip/hip_bf16.h>
#include <cstdint>
#include <cstddef>

typedef unsigned short u16;
typedef unsigned int u32;
typedef __attribute__((ext_vector_type(4))) float f32x4;
typedef __attribute__((ext_vector_type(8))) __bf16 bf16x8;

#define EPS_F 1.1920928955078125e-07f
#define INV_SQRT_D 0.08838834764831845f
#define LOG2E 1.4426950408889634f

__device__ __forceinline__ u16 f2bf(float f) {
  union { float f; u32 u; } v; v.f = f;
  u32 r = v.u + 0x7fffu + ((v.u >> 16) & 1u);
  return (u16)(r >> 16);
}
__device__ __forceinline__ float bf2f(u16 u) {
  union { u32 u; float f; } v; v.u = (u32)u << 16; return v.f;
}
__device__ __forceinline__ ushort4 pack_bf4(float a, float b, float c, float d) {
  ushort4 o; o.x = f2bf(a); o.y = f2bf(b); o.z = f2bf(c); o.w = f2bf(d); return o;
}
__device__ __forceinline__ float4 ld4bf(const u16* p) {
  ushort4 u = *(const ushort4*)p;
  float4 f; f.x = bf2f(u.x); f.y = bf2f(u.y); f.z = bf2f(u.z); f.w = bf2f(u.w); return f;
}
__device__ __forceinline__ void gload_lds16(const void* g, void* l) {
  __builtin_amdgcn_global_load_lds((const __attribute__((address_space(1))) u32*)g,
                                   (__attribute__((address_space(3))) u32*)l, 16, 0, 0);
}

#define MIDBAR() do { __builtin_amdgcn_s_barrier(); \
  asm volatile("s_waitcnt lgkmcnt(0)" ::: "memory"); \
  __builtin_amdgcn_sched_barrier(0); } while (0)
#define ENDBAR() do { __builtin_amdgcn_s_barrier(); \
  __builtin_amdgcn_sched_barrier(0); } while (0)

// ---------------- cast f32 -> bf16 ----------------
__global__ __launch_bounds__(256) void k_cast_bf16(const float* __restrict__ src,
                                                   u16* __restrict__ dst, int n) {
  int i = (blockIdx.x * 256 + threadIdx.x) * 4;
  if (i + 3 < n) {
    float4 v = *(const float4*)(src + i);
    *(ushort4*)(dst + i) = pack_bf4(v.x, v.y, v.z, v.w);
  }
}

// ---------------- 256x256 8-phase bf16 GEMM, C = A * Bw^T, bf16 out ----------------
// A: M x K, Bw: N x K, Cb: M x N (bf16). 8 waves (2M x 4N), BK=64, 128KiB LDS.
// Stage ledger (iter i computes K-tiles 2i [buf0], 2i+1 [buf1]):
//   ph1: A1h0<-t1  ph2: A1h1<-t1  ph3: B0h0<-t2  ph4: B0h1<-t2 [vmcnt(4)]
//   ph5: A0h0<-t2  ph6: A0h1<-t2  ph7: B1h0<-t3  ph8: B1h1<-t3 [vmcnt(4)]
// Slot last-reads: A halves ph1&3 (buf0)/ph5&7 (buf1); B halves ph1&2 / ph5&6.
// Every stage targets a slot freed >=1 phase earlier; every read is covered by
// the preceding gate (vmcnt(4) leaves exactly the 2 newest half-tiles in flight).
__global__ __launch_bounds__(512, 2) void k_gemm256(const u16* __restrict__ A,
                                                    const u16* __restrict__ Bw,
                                                    u16* __restrict__ Cb,
                                                    int M, int N, int K) {
  __shared__ __align__(16) u16 As[2][2][8192];  // [buf][half][128*64]
  __shared__ __align__(16) u16 Bs[2][2][8192];
  const int tid = threadIdx.x;
  const int lane = tid & 63;
  const int wid = tid >> 6;           // 0..7
  const int wm = wid >> 2;            // 0..1
  const int wn = wid & 3;             // 0..3
  const int l15 = lane & 15, l4 = lane >> 4;
  const int nKt = K >> 6;
  const int nIt = nKt >> 1;

  const u16* Ab = A + (size_t)blockIdx.x * 256 * K;
  const u16* Bb = Bw + (size_t)blockIdx.y * 256 * K;

  f32x4 acc[8][4];
#pragma unroll
  for (int i = 0; i < 8; ++i)
#pragma unroll
    for (int j = 0; j < 4; ++j) acc[i][j] = {0.f, 0.f, 0.f, 0.f};

  bf16x8 aReg[4][2];      // current m-half fragments
  bf16x8 bReg[2][2][2];   // both n-half fragments kept

  auto stage = [&](const u16* gbase, u16* slot) {
#pragma unroll
    for (int j = 0; j < 2; ++j) {
      const int idx = j * 512 + tid;
      const int row = idx >> 3;
      const int gg = (idx & 7) ^ (row & 7);        // inverse-swizzled source
      gload_lds16(gbase + (size_t)row * K + gg * 8,
                  slot + (size_t)(j * 512 + wid * 64) * 8);  // linear dest
    }
  };
  auto ldA = [&](int buf, int mh) {
    const u16* base = As[buf][wm];
#pragma unroll
    for (int mf = 0; mf < 4; ++mf) {
      const int rh = (mh * 4 + mf) * 16 + l15;
#pragma unroll
      for (int kk = 0; kk < 2; ++kk) {
        const int g = (kk * 4 + l4) ^ (rh & 7);    // swizzled read
        aReg[mf][kk] = *(const bf16x8*)&base[rh * 64 + g * 8];
      }
    }
  };
  auto ldB = [&](int buf, int nh) {
    const u16* base = Bs[buf][wn >> 1];
#pragma unroll
    for (int nf = 0; nf < 2; ++nf) {
      const int rh = (wn & 1) * 64 + (nh * 2 + nf) * 16 + l15;
#pragma unroll
      for (int kk = 0; kk < 2; ++kk) {
        const int g = (kk * 4 + l4) ^ (rh & 7);
        bReg[nh][nf][kk] = *(const bf16x8*)&base[rh * 64 + g * 8];
      }
    }
  };
  auto mm = [&](int mh, int nh) {
    __builtin_amdgcn_s_setprio(1);
#pragma unroll
    for (int kk = 0; kk < 2; ++kk)
#pragma unroll
      for (int mf = 0; mf < 4; ++mf)
#pragma unroll
        for (int nf = 0; nf < 2; ++nf)
          acc[mh * 4 + mf][nh * 2 + nf] = __builtin_amdgcn_mfma_f32_16x16x32_bf16(
              aReg[mf][kk], bReg[nh][nf][kk], acc[mh * 4 + mf][nh * 2 + nf], 0, 0, 0);
    __builtin_amdgcn_s_setprio(0);
  };

  const size_t hK = (size_t)128 * K;
  // prologue: buf0 <- tile0 (4 half-tiles), B-buf1 <- tile1 (2 half-tiles)
  stage(Bb, &Bs[0][0][0]);
  stage(Bb + hK, &Bs[0][1][0]);
  stage(Ab, &As[0][0][0]);
  stage(Ab + hK, &As[0][1][0]);
  stage(Bb + 64, &Bs[1][0][0]);
  stage(Bb + hK + 64, &Bs[1][1][0]);
  asm volatile("s_waitcnt vmcnt(4)" ::: "memory");
  __builtin_amdgcn_s_barrier();
  __builtin_amdgcn_sched_barrier(0);

#pragma unroll 1
  for (int i = 0; i < nIt; ++i) {
    const int t1 = 2 * i + 1;
    const int t2 = (2 * i + 2 < nKt) ? 2 * i + 2 : nKt - 1;  // clamped (landed, never read)
    const int t3 = (2 * i + 3 < nKt) ? 2 * i + 3 : nKt - 1;
    const size_t o1 = (size_t)t1 * 64, o2 = (size_t)t2 * 64, o3 = (size_t)t3 * 64;

    // ph1
    ldA(0, 0); ldB(0, 0); stage(Ab + o1, &As[1][0][0]);
    MIDBAR(); mm(0, 0); ENDBAR();
    // ph2
    ldB(0, 1); stage(Ab + hK + o1, &As[1][1][0]);
    MIDBAR(); mm(0, 1); ENDBAR();
    // ph3
    ldA(0, 1); stage(Bb + o2, &Bs[0][0][0]);
    MIDBAR(); mm(1, 1); ENDBAR();
    // ph4
    stage(Bb + hK + o2, &Bs[0][1][0]);
    MIDBAR(); mm(1, 0);
    asm volatile("s_waitcnt vmcnt(4)" ::: "memory");
    ENDBAR();
    // ph5
    ldA(1, 0); ldB(1, 0); stage(Ab + o2, &As[0][0][0]);
    MIDBAR(); mm(0, 0); ENDBAR();
    // ph6
    ldB(1, 1); stage(Ab + hK + o2, &As[0][1][0]);
    MIDBAR(); mm(0, 1); ENDBAR();
    // ph7
    ldA(1, 1); stage(Bb + o3, &Bs[1][0][0]);
    MIDBAR(); mm(1, 1); ENDBAR();
    // ph8
    stage(Bb + hK + o3, &Bs[1][1][0]);
    MIDBAR(); mm(1, 0);
    asm volatile("s_waitcnt vmcnt(4)" ::: "memory");
    ENDBAR();
  }

  const int r0 = blockIdx.x * 256 + wm * 128 + l4 * 4;
  const int c0 = blockIdx.y * 256 + wn * 64 + l15;
#pragma unroll
  for (int i2 = 0; i2 < 8; ++i2)
#pragma unroll
    for (int j2 = 0; j2 < 4; ++j2)
#pragma unroll
      for (int r = 0; r < 4; ++r)
        Cb[(size_t)(r0 + i2 * 16 + r) * N + c0 + j2 * 16] = f2bf(acc[i2][j2][r]);
}

// ---------------- bf16 GEMM 128x128 (m97 structure), fp32 out — out-proj ----------------
__global__ __launch_bounds__(256) void k_gemm_bt(const u16* __restrict__ A,
                                                 const u16* __restrict__ Bw,
                                                 float* __restrict__ C,
                                                 int M, int N, int K) {
  __shared__ __align__(16) u16 As[128 * 32];
  __shared__ __align__(16) u16 Bs[128 * 32];
  const int tid = threadIdx.x;
  const int lane = tid & 63;
  const int wid = tid >> 6;
  const int wm = wid >> 1, wn = wid & 1;
  const int l15 = lane & 15, l4 = lane >> 4;

  f32x4 acc[4][4];
#pragma unroll
  for (int i = 0; i < 4; ++i)
#pragma unroll
    for (int j = 0; j < 4; ++j) acc[i][j] = {0.f, 0.f, 0.f, 0.f};

  const u16* Ab = A + (size_t)blockIdx.x * 128 * K;
  const u16* Bb = Bw + (size_t)blockIdx.y * 128 * K;
  const int lrow = lane >> 2;
  const int scol = ((lane & 3) ^ ((lane >> 3) & 3)) * 8;
  const int rswz = (l15 >> 1) & 3;

  for (int k0 = 0; k0 < K; k0 += 32) {
    __syncthreads();
#pragma unroll
    for (int p = 0; p < 2; ++p) {
      const int chunk = wid * 2 + p;
      const int row = chunk * 16 + lrow;
      gload_lds16(Ab + (size_t)row * K + k0 + scol, &As[chunk * 512]);
      gload_lds16(Bb + (size_t)row * K + k0 + scol, &Bs[chunk * 512]);
    }
    __syncthreads();
    bf16x8 af[4], bfv[4];
#pragma unroll
    for (int i = 0; i < 4; ++i) {
      const int cb = (l4 ^ rswz) * 8;
      af[i]  = *(const bf16x8*)&As[(wm * 64 + i * 16 + l15) * 32 + cb];
      bfv[i] = *(const bf16x8*)&Bs[(wn * 64 + i * 16 + l15) * 32 + cb];
    }
#pragma unroll
    for (int i = 0; i < 4; ++i)
#pragma unroll
      for (int j = 0; j < 4; ++j)
        acc[i][j] = __builtin_amdgcn_mfma_f32_16x16x32_bf16(af[i], bfv[j], acc[i][j], 0, 0, 0);
  }

  const int r0 = blockIdx.x * 128 + wm * 64 + l4 * 4;
  const int c0 = blockIdx.y * 128 + wn * 64 + l15;
#pragma unroll
  for (int i = 0; i < 4; ++i)
#pragma unroll
    for (int j = 0; j < 4; ++j) {
      float* Cp = C + (size_t)(r0 + i * 16) * N + c0 + j * 16;
#pragma unroll
      for (int r = 0; r < 4; ++r) Cp[(size_t)r * N] = acc[i][j][r];
    }
}

// ---------------- rope + rmsnorm + scale + cast (bf16 in) ----------------
__global__ __launch_bounds__(256) void k_rope_rms(const u16* __restrict__ qkv,
                                                  const float* __restrict__ cosp,
                                                  const float* __restrict__ sinp,
                                                  u16* __restrict__ qb, u16* __restrict__ kb,
                                                  u16* __restrict__ vb) {
  const int T = 2048;
  const int m = blockIdx.x;
  const int b = m >> 11;
  const int t = m & 2047;
  const int tid = threadIdx.x;
  const int h = tid >> 4;
  const int d0 = (tid & 15) * 4;
  const size_t ro = (size_t)m * 6144 + h * 128;

  float4 q1 = ld4bf(qkv + ro + d0);
  float4 q2 = ld4bf(qkv + ro + d0 + 64);
  float4 k1 = ld4bf(qkv + ro + 2048 + d0);
  float4 k2 = ld4bf(qkv + ro + 2048 + d0 + 64);
  float4 v1 = ld4bf(qkv + ro + 4096 + d0);
  float4 v2 = ld4bf(qkv + ro + 4096 + d0 + 64);
  float4 cs = *(const float4*)(cosp + (size_t)t * 64 + d0);
  float4 sn = *(const float4*)(sinp + (size_t)t * 64 + d0);

  float sq = q1.x*q1.x + q1.y*q1.y + q1.z*q1.z + q1.w*q1.w
           + q2.x*q2.x + q2.y*q2.y + q2.z*q2.z + q2.w*q2.w;
  float sk = k1.x*k1.x + k1.y*k1.y + k1.z*k1.z + k1.w*k1.w
           + k2.x*k2.x + k2.y*k2.y + k2.z*k2.z + k2.w*k2.w;
#pragma unroll
  for (int o = 1; o < 16; o <<= 1) {
    sq += __shfl_xor(sq, o, 64);
    sk += __shfl_xor(sk, o, 64);
  }
  const float rq = rsqrtf(sq * (1.f / 128.f) + EPS_F) * (INV_SQRT_D * LOG2E);
  const float rk = rsqrtf(sk * (1.f / 128.f) + EPS_F);

  const size_t ob = ((size_t)(b * 16 + h) * T + t) * 128 + d0;
  *(ushort4*)(qb + ob) = pack_bf4((q1.x*cs.x + q2.x*sn.x) * rq, (q1.y*cs.y + q2.y*sn.y) * rq,
                                  (q1.z*cs.z + q2.z*sn.z) * rq, (q1.w*cs.w + q2.w*sn.w) * rq);
  *(ushort4*)(qb + ob + 64) = pack_bf4((q2.x*cs.x - q1.x*sn.x) * rq, (q2.y*cs.y - q1.y*sn.y) * rq,
                                       (q2.z*cs.z - q1.z*sn.z) * rq, (q2.w*cs.w - q1.w*sn.w) * rq);
  *(ushort4*)(kb + ob) = pack_bf4((k1.x*cs.x + k2.x*sn.x) * rk, (k1.y*cs.y + k2.y*sn.y) * rk,
                                  (k1.z*cs.z + k2.z*sn.z) * rk, (k1.w*cs.w + k2.w*sn.w) * rk);
  *(ushort4*)(kb + ob + 64) = pack_bf4((k2.x*cs.x - k1.x*sn.x) * rk, (k2.y*cs.y - k1.y*sn.y) * rk,
                                       (k2.z*cs.z - k1.z*sn.z) * rk, (k2.w*cs.w - k1.w*sn.w) * rk);
  *(ushort4*)(vb + ob) = pack_bf4(v1.x, v1.y, v1.z, v1.w);
  *(ushort4*)(vb + ob + 64) = pack_bf4(v2.x, v2.y, v2.z, v2.w);
}

// ---------------- V transpose: [bh][t][d] -> [bh][d][t] ----------------
__global__ __launch_bounds__(256) void k_transpose_v(const u16* __restrict__ vb,
                                                     u16* __restrict__ vt) {
  const int T = 2048;
  __shared__ u16 tile[32][33];
  const int bh = blockIdx.z;
  const int t0 = blockIdx.x * 32;
  const int d0 = blockIdx.y * 32;
  const int tx = threadIdx.x & 31;
  const int ty = threadIdx.x >> 5;
  const size_t base = (size_t)bh * T * 128;
#pragma unroll
  for (int i = 0; i < 4; ++i)
    tile[ty + i * 8][tx] = vb[base + (size_t)(t0 + ty + i * 8) * 128 + d0 + tx];
  __syncthreads();
#pragma unroll
  for (int i = 0; i < 4; ++i)
    vt[base + (size_t)(d0 + ty + i * 8) * T + t0 + tx] = tile[tx][ty + i * 8];
}

// ---------------- causal flash attention ----------------
__global__ __launch_bounds__(256) void k_attn(const u16* __restrict__ qb,
                                              const u16* __restrict__ kb,
                                              const u16* __restrict__ vt,
                                              u16* __restrict__ y) {
  const int T = 2048;
  __shared__ __align__(16) u16 Ks[2][64 * 128];
  __shared__ __align__(16) u16 Vs[2][128 * 64];
  __shared__ __align__(16) u16 Ps[64 * 72];

  const int tid = threadIdx.x;
  const int lane = tid & 63;
  const int wid = tid >> 6;
  const int bh = blockIdx.y;
  const int b = bh >> 4, h = bh & 15;
  const size_t hb = (size_t)bh * T * 128;
  const int l15 = lane & 15, l4 = lane >> 4;

  auto stage = [&](int it, int buf) {
#pragma unroll
    for (int p = 0; p < 4; ++p) {
      const int chunk = wid * 4 + p;
      {
        const int row = chunk * 4 + l4;
        const int scb = l15 ^ (row & 7);
        gload_lds16(kb + hb + (size_t)(it * 64 + row) * 128 + scb * 8, &Ks[buf][chunk * 512]);
      }
      {
        const int row = chunk * 8 + (lane >> 3);
        const int scb = (lane & 7) ^ (row & 7);
        gload_lds16(vt + hb + (size_t)row * T + it * 64 + scb * 8, &Vs[buf][chunk * 512]);
      }
    }
  };

#pragma unroll 1
  for (int ph = 0; ph < 2; ++ph) {
    const int qt = (ph == 0) ? (int)blockIdx.x : 31 - (int)blockIdx.x;
    const int q0 = qt * 64;
    const int niter = qt + 1;

    bf16x8 qf[4];
    {
      const int qrow = q0 + wid * 16 + l15;
#pragma unroll
      for (int ki = 0; ki < 4; ++ki)
        qf[ki] = *(const bf16x8*)(qb + hb + (size_t)qrow * 128 + ki * 32 + l4 * 8);
    }

    float mrow[4], lsum[4];
    f32x4 oacc[8];
#pragma unroll
    for (int r = 0; r < 4; ++r) { mrow[r] = -INFINITY; lsum[r] = 0.f; }
#pragma unroll
    for (int d = 0; d < 8; ++d) oacc[d] = {0.f, 0.f, 0.f, 0.f};

    stage(0, 0);
    asm volatile("s_waitcnt vmcnt(0)" ::: "memory");
    __builtin_amdgcn_s_barrier();
    __builtin_amdgcn_sched_barrier(0);

    int cur = 0;
#pragma unroll 1
    for (int it = 0; it < niter; ++it) {
      if (it + 1 < niter) stage(it + 1, cur ^ 1);

      f32x4 s[4];
#pragma unroll
      for (int ni = 0; ni < 4; ++ni) {
        s[ni] = {0.f, 0.f, 0.f, 0.f};
        const int r = ni * 16 + l15;
#pragma unroll
        for (int ki = 0; ki < 4; ++ki) {
          const int cb = (ki * 4 + l4) ^ (r & 7);
          bf16x8 kf = *(const bf16x8*)&Ks[cur][r * 128 + cb * 8];
          s[ni] = __builtin_amdgcn_mfma_f32_16x16x32_bf16(qf[ki], kf, s[ni], 0, 0, 0);
        }
      }

      if (it == niter - 1) {
        const int grow = q0 + wid * 16 + l4 * 4;
        const int gcol = it * 64 + l15;
#pragma unroll
        for (int ni = 0; ni < 4; ++ni)
#pragma unroll
          for (int r = 0; r < 4; ++r)
            if (gcol + ni * 16 > grow + r) s[ni][r] = -INFINITY;
      }

      float pv[4][4];
      float alpha[4];
#pragma unroll
      for (int r = 0; r < 4; ++r) {
        float mx = fmaxf(fmaxf(s[0][r], s[1][r]), fmaxf(s[2][r], s[3][r]));
#pragma unroll
        for (int o = 1; o < 16; o <<= 1) mx = fmaxf(mx, __shfl_xor(mx, o, 64));
        const float mnew = fmaxf(mrow[r], mx);
        alpha[r] = exp2f(mrow[r] - mnew);
        mrow[r] = mnew;
        float ps = 0.f;
#pragma unroll
        for (int ni = 0; ni < 4; ++ni) {
          const float p = exp2f(s[ni][r] - mnew);
          pv[ni][r] = p;
          ps += p;
        }
#pragma unroll
        for (int o = 1; o < 16; o <<= 1) ps += __shfl_xor(ps, o, 64);
        lsum[r] = lsum[r] * alpha[r] + ps;
      }
#pragma unroll
      for (int d = 0; d < 8; ++d) {
        f32x4 tv = oacc[d];
        tv[0] *= alpha[0]; tv[1] *= alpha[1]; tv[2] *= alpha[2]; tv[3] *= alpha[3];
        oacc[d] = tv;
      }
#pragma unroll
      for (int ni = 0; ni < 4; ++ni)
#pragma unroll
        for (int r = 0; r < 4; ++r)
          Ps[(wid * 16 + l4 * 4 + r) * 72 + ni * 16 + l15] = f2bf(pv[ni][r]);

#pragma unroll
      for (int k2 = 0; k2 < 2; ++k2) {
        bf16x8 pa = *(const bf16x8*)&Ps[(wid * 16 + l15) * 72 + k2 * 32 + l4 * 8];
#pragma unroll
        for (int dt = 0; dt < 8; ++dt) {
          const int r = dt * 16 + l15;
          const int cb = (k2 * 4 + l4) ^ (r & 7);
          bf16x8 vf = *(const bf16x8*)&Vs[cur][r * 64 + cb * 8];
          oacc[dt] = __builtin_amdgcn_mfma_f32_16x16x32_bf16(pa, vf, oacc[dt], 0, 0, 0);
        }
      }

      asm volatile("s_waitcnt vmcnt(0)" ::: "memory");
      __builtin_amdgcn_s_barrier();
      __builtin_amdgcn_sched_barrier(0);
      cur ^= 1;
    }

#pragma unroll
    for (int r = 0; r < 4; ++r) {
      const float inv = 1.f / lsum[r];
      const size_t yo = ((size_t)(b * T) + q0 + wid * 16 + l4 * 4 + r) * 2048 + h * 128;
#pragma unroll
      for (int dt = 0; dt < 8; ++dt)
        y[yo + dt * 16 + l15] = f2bf(oacc[dt][r] * inv);
    }
  }
}

// ---------------- launcher ----------------
extern "C" void kernel_launch(void* const* d_in, const int* in_sizes, int n_in,
                              void* d_out, int out_size, void* d_ws, size_t ws_size,
                              hipStream_t stream) {
  const float* x     = (const float*)d_in[0];
  const float* cosp  = (const float*)d_in[1];
  const float* sinp  = (const float*)d_in[2];
  const float* wq    = (const float*)d_in[3];
  const float* wk    = (const float*)d_in[4];
  const float* wv    = (const float*)d_in[5];
  const float* wproj = (const float*)d_in[6];
  float* out = (float*)d_out;

  const int T = 2048, C = 2048;
  const int M = 2 * T;
  const int N1 = 3 * C;

  char* ws = (char*)d_ws;
  size_t off = 0;
  auto take = [&](size_t bytes) -> char* {
    char* p = ws + off;
    off += (bytes + 255) & ~(size_t)255;
    return p;
  };
  u16* xb    = (u16*)take((size_t)M * C * 2);
  u16* wqkvb = (u16*)take((size_t)N1 * C * 2);
  u16* wpb   = (u16*)take((size_t)C * C * 2);
  u16* qkvb  = (u16*)take((size_t)M * N1 * 2);
  u16* qb    = (u16*)take((size_t)M * C * 2);
  u16* kb    = (u16*)take((size_t)M * C * 2);
  u16* vb    = (u16*)take((size_t)M * C * 2);
  u16* vt    = (u16*)take((size_t)M * C * 2);
  u16* yb    = (u16*)take((size_t)M * C * 2);
  (void)ws_size; (void)in_sizes; (void)n_in; (void)out_size;

  const int nx = M * C;
  const int nw = C * C;
  k_cast_bf16<<<nx / 1024, 256, 0, stream>>>(x, xb, nx);
  k_cast_bf16<<<nw / 1024, 256, 0, stream>>>(wq, wqkvb, nw);
  k_cast_bf16<<<nw / 1024, 256, 0, stream>>>(wk, wqkvb + (size_t)C * C, nw);
  k_cast_bf16<<<nw / 1024, 256, 0, stream>>>(wv, wqkvb + (size_t)2 * C * C, nw);
  k_cast_bf16<<<nw / 1024, 256, 0, stream>>>(wproj, wpb, nw);

  k_gemm256<<<dim3(M / 256, N1 / 256), 512, 0, stream>>>(xb, wqkvb, qkvb, M, N1, C);
  k_rope_rms<<<M, 256, 0, stream>>>(qkvb, cosp, sinp, qb, kb, vb);
  k_transpose_v<<<dim3(T / 32, 128 / 32, 32), 256, 0, stream>>>(vb, vt);
  k_attn<<<dim3(16, 32), 256, 0, stream>>>(qb, kb, vt, yb);
  k_gemm_bt<<<dim3(M / 128, C / 128), 256, 0, stream>>>(yb, wpb, out, M, C, C);
}